// Round 3
// baseline (41.019 us; speedup 1.0000x reference)
//
#include <hip/hip_runtime.h>

#define DEGREE 32
#define DIMS 8
#define NB 32
#define NPOS 65536
#define BLOCK 256
#define PPT 4                       // positions per thread, strided by BLOCK
#define SPAN (BLOCK * PPT)          // 1024 positions per block
// 64 blocks per batch -> b = blockIdx.x >> 6

// K = -12.5 * log2(e)  :  exp(-(x-c)^2 * 12.5) = exp2(K*(x-c)^2)
//                       = exp2( K*x*x + (-2*K*c)*x + K*c*c )
#define K_EXP2 (-18.033688011112043f)
#define CSTEP  (1.01f / 31.0f)

__global__ __launch_bounds__(BLOCK) void basis_kernel(
    const float* __restrict__ weights,    // (B, DIMS, DEGREE)
    const float* __restrict__ positions,  // (B, N)
    float* __restrict__ out,              // (B, N, DIMS)
    float* __restrict__ out_zero)         // (B, N, DIMS) -> all zeros
{
    const int b    = blockIdx.x >> 6;
    const int nblk = blockIdx.x & 63;
    const int tid  = threadIdx.x;
    const int n0   = nblk * SPAN + tid;

    const float* __restrict__ wb = weights + b * (DIMS * DEGREE);
    const size_t posBase = (size_t)b * NPOS + n0;
    const size_t outBase = posBase * DIMS;

    // --- zeros first: independent of compute, primes the write pipe ---
    const float4 zz = make_float4(0.0f, 0.0f, 0.0f, 0.0f);
    #pragma unroll
    for (int k = 0; k < PPT; ++k) {
        float4* z = reinterpret_cast<float4*>(out_zero + outBase + (size_t)k * BLOCK * DIMS);
        z[0] = zz;
        z[1] = zz;
    }

    // --- load 4 positions (stride BLOCK -> each load coalesced) ---
    float x[PPT], t[PPT];
    #pragma unroll
    for (int k = 0; k < PPT; ++k) {
        x[k] = positions[posBase + (size_t)k * BLOCK];
        t[k] = K_EXP2 * x[k] * x[k];
    }

    float acc[PPT][DIMS];
    #pragma unroll
    for (int k = 0; k < PPT; ++k)
        #pragma unroll
        for (int d = 0; d < DIMS; ++d)
            acc[k][d] = 0.0f;

    // --- full unroll: per-g constants fold to literals, weights stay scalar ---
    #pragma unroll
    for (int g = 0; g < DEGREE; ++g) {
        const float c  = CSTEP * (float)g;
        const float bg = -2.0f * K_EXP2 * c;
        const float ag = K_EXP2 * c * c;
        float w[DIMS];
        #pragma unroll
        for (int d = 0; d < DIMS; ++d) w[d] = wb[d * DEGREE + g];  // uniform -> s_load
        float e[PPT];
        #pragma unroll
        for (int k = 0; k < PPT; ++k)
            e[k] = __builtin_amdgcn_exp2f(t[k] + fmaf(bg, x[k], ag));
        #pragma unroll
        for (int k = 0; k < PPT; ++k)
            #pragma unroll
            for (int d = 0; d < DIMS; ++d)
                acc[k][d] = fmaf(e[k], w[d], acc[k][d]);
    }

    // --- result stores (each float4 instruction fully coalesced) ---
    #pragma unroll
    for (int k = 0; k < PPT; ++k) {
        float4* o = reinterpret_cast<float4*>(out + outBase + (size_t)k * BLOCK * DIMS);
        o[0] = make_float4(acc[k][0], acc[k][1], acc[k][2], acc[k][3]);
        o[1] = make_float4(acc[k][4], acc[k][5], acc[k][6], acc[k][7]);
    }
}

extern "C" void kernel_launch(void* const* d_in, const int* in_sizes, int n_in,
                              void* d_out, int out_size, void* d_ws, size_t ws_size,
                              hipStream_t stream) {
    const float* weights   = (const float*)d_in[0];
    // d_in[1] = weights_std: unused (second output is exactly zeros)
    const float* positions = (const float*)d_in[2];

    float* out      = (float*)d_out;
    float* out_zero = out + (size_t)NB * NPOS * DIMS;

    dim3 grid(NB * (NPOS / SPAN));   // 32 * 64 = 2048 blocks
    dim3 block(BLOCK);
    basis_kernel<<<grid, block, 0, stream>>>(weights, positions, out, out_zero);
}

// Round 4
// 29.904 us; speedup vs baseline: 1.3717x; 1.3717x over previous
//
#include <hip/hip_runtime.h>

#define DEGREE 32
#define DIMS 8
#define NB 32
#define NPOS 65536
#define BLOCK 256

// exp(-(x-c)^2/(2*0.04)) = exp2( (x-c)^2 * K ),  K = -12.5*log2(e)
#define K_EXP2 (-18.033688011112043f)
#define CSTEP  (1.01f / 31.0f)

#define NCOMP 8192   // 32 batches * 256 blocks, 1 position per thread
#define NFILL 2048   // zero half: 4,194,304 float4 = 524,288 threads * 8

typedef __attribute__((ext_vector_type(2))) float f32x2;

__global__ __launch_bounds__(BLOCK) void basis_kernel(
    const float* __restrict__ weights,    // (B, DIMS, DEGREE)
    const float* __restrict__ positions,  // (B, N)
    float* __restrict__ out,              // (B, N, DIMS)
    float* __restrict__ out_zero)         // (B, N, DIMS) -> zeros
{
    const int bid = blockIdx.x;
    const int tid = threadIdx.x;

    // ---- role split: every 5th block is a pure zero-filler ----
    if ((bid % 5) == 4) {
        const int f = bid / 5;                       // 0..NFILL-1
        float4* z = reinterpret_cast<float4*>(out_zero);
        const float4 zz = make_float4(0.0f, 0.0f, 0.0f, 0.0f);
        size_t idx = (size_t)f * BLOCK + tid;        // 0..524287
        #pragma unroll
        for (int k = 0; k < 8; ++k)
            z[idx + (size_t)k * ((size_t)NFILL * BLOCK)] = zz;
        return;
    }

    // ---- compute role ----
    const int cb = bid - bid / 5;                    // 0..NCOMP-1
    const int b  = cb >> 8;
    const int n  = ((cb & 255) << 8) + tid;

    const float* __restrict__ wb = weights + b * (DIMS * DEGREE);
    const float x = positions[(size_t)b * NPOS + n];

    f32x2 acc[DIMS];
    #pragma unroll
    for (int d = 0; d < DIMS; ++d) { acc[d].x = 0.0f; acc[d].y = 0.0f; }

    float c = 0.0f;
    #pragma unroll 4
    for (int gp = 0; gp < DEGREE / 2; ++gp) {
        const float d0 = x - c;
        const float d1 = d0 - CSTEP;
        const float e0 = __builtin_amdgcn_exp2f(d0 * d0 * K_EXP2);
        const float e1 = __builtin_amdgcn_exp2f(d1 * d1 * K_EXP2);
        f32x2 e2; e2.x = e0; e2.y = e1;
        const int g = gp * 2;
        #pragma unroll
        for (int d = 0; d < DIMS; ++d) {
            // adjacent g contiguous in memory; uniform addr -> s_load_dwordx2
            f32x2 w2 = *reinterpret_cast<const f32x2*>(wb + d * DEGREE + g);
            acc[d] = __builtin_elementwise_fma(e2, w2, acc[d]);  // v_pk_fma_f32
        }
        c += 2.0f * CSTEP;
    }

    float r[DIMS];
    #pragma unroll
    for (int d = 0; d < DIMS; ++d) r[d] = acc[d].x + acc[d].y;

    const size_t base = ((size_t)b * NPOS + n) * DIMS;
    float4* o = reinterpret_cast<float4*>(out + base);
    o[0] = make_float4(r[0], r[1], r[2], r[3]);
    o[1] = make_float4(r[4], r[5], r[6], r[7]);
}

extern "C" void kernel_launch(void* const* d_in, const int* in_sizes, int n_in,
                              void* d_out, int out_size, void* d_ws, size_t ws_size,
                              hipStream_t stream) {
    const float* weights   = (const float*)d_in[0];
    // d_in[1] = weights_std: unused (second output is exactly zeros)
    const float* positions = (const float*)d_in[2];

    float* out      = (float*)d_out;
    float* out_zero = out + (size_t)NB * NPOS * DIMS;

    dim3 grid(NCOMP + NFILL);   // 10240 blocks, roles interleaved 4:1
    dim3 block(BLOCK);
    basis_kernel<<<grid, block, 0, stream>>>(weights, positions, out, out_zero);
}